// Round 5
// baseline (1569.096 us; speedup 1.0000x reference)
//
#include <hip/hip_runtime.h>

typedef unsigned short ushort_t;
typedef __bf16 v8bf __attribute__((ext_vector_type(8)));
typedef float v4f __attribute__((ext_vector_type(4)));

#define B_ 32
#define N_ 1024
#define C_ 768
#define G_ 8
#define HD_ 96
#define CH_ 3072
#define M_ 32768  // B*N

static __device__ __forceinline__ float b2f(ushort_t u) {
    union { float f; unsigned int i; } z; z.i = ((unsigned int)u) << 16; return z.f;
}
static __device__ __forceinline__ ushort_t f2b(float f) {
    unsigned int u = __float_as_uint(f);
    u += 0x7fff + ((u >> 16) & 1);   // RNE
    return (ushort_t)(u >> 16);
}
static __device__ __forceinline__ unsigned int pk2(float a, float b) {
    return (unsigned int)f2b(a) | ((unsigned int)f2b(b) << 16);
}

#define GLOAD_LDS16(g, l) __builtin_amdgcn_global_load_lds( \
    (const __attribute__((address_space(1))) unsigned int*)(g), \
    (__attribute__((address_space(3))) unsigned int*)(l), 16, 0, 0)

// ---------------- fp32 -> bf16 weight conversion (4 elems/thread) -------------
__global__ __launch_bounds__(256) void cvt_bf16(
    const float* __restrict__ in, ushort_t* __restrict__ out)
{
    int i = (blockIdx.x * 256 + threadIdx.x) * 4;
    float4 v = *(const float4*)(in + i);
    uint2 p; p.x = pk2(v.x, v.y); p.y = pk2(v.z, v.w);
    *(uint2*)(out + i) = p;
}

// ---------------- dwconv weight transpose: [C,3,3] -> [9][C] fp32 -------------
__global__ __launch_bounds__(256) void transpose_w(
    const float* __restrict__ w, float* __restrict__ wt)
{
    int i = blockIdx.x * 256 + threadIdx.x;   // exactly 6912 = 27*256
    int c = i / 9, k = i % 9;
    wt[k * C_ + c] = w[i];
}

// ---------------- depthwise 3x3 conv + residual (fp32): out = x + conv(x) ----
__global__ __launch_bounds__(256) void dwconv_add(
    const float* __restrict__ xin, const float* __restrict__ wt,
    const float* __restrict__ bias, float* __restrict__ out)
{
    int t = threadIdx.x;
    int bid = blockIdx.x;
    int cblk = bid % 6;                  // 6 = 768/128
    int bh = bid / 6;                    // b*32 + h
    int b = bh >> 5, h = bh & 31;
    int tw = t >> 5;                     // 0..7  -> 4-pixel group
    int c0 = cblk * 128 + (t & 31) * 4;  // channel base (float4)
    int w0 = tw * 4;

    float4 tap[3][6];
#pragma unroll
    for (int dh = 0; dh < 3; dh++) {
        int hh = h + dh - 1;
        bool hok = (hh >= 0) && (hh < 32);   // block-uniform branch
#pragma unroll
        for (int dw = 0; dw < 6; dw++) {
            int ww = w0 + dw - 1;
            bool ok = hok && (ww >= 0) && (ww < 32);
            if (ok)
                tap[dh][dw] = *(const float4*)(
                    xin + (size_t)((b << 10) | (hh << 5) | ww) * C_ + c0);
            else
                tap[dh][dw] = make_float4(0.f, 0.f, 0.f, 0.f);
        }
    }
    float4 wv[9];
#pragma unroll
    for (int k = 0; k < 9; k++)
        wv[k] = *(const float4*)(wt + k * C_ + c0);
    float4 bv = *(const float4*)(bias + c0);

#pragma unroll
    for (int i = 0; i < 4; i++) {
        float4 acc = bv;
#pragma unroll
        for (int dh = 0; dh < 3; dh++)
#pragma unroll
            for (int dw = 0; dw < 3; dw++) {
                float4 xv = tap[dh][i + dw];
                float4 wk = wv[dh * 3 + dw];
                acc.x += wk.x * xv.x; acc.y += wk.y * xv.y;
                acc.z += wk.z * xv.z; acc.w += wk.w * xv.w;
            }
        float4 xr = tap[1][i + 1];
        acc.x += xr.x; acc.y += xr.y; acc.z += xr.z; acc.w += xr.w;
        *(float4*)(out + (size_t)((b << 10) | (h << 5) | (w0 + i)) * C_ + c0) = acc;
    }
}

// ---------------- layernorm over C=768: fp32 in -> bf16 out -------------------
__global__ __launch_bounds__(256) void layernorm_bf(
    const float* __restrict__ xin, const float* __restrict__ g,
    const float* __restrict__ bb, ushort_t* __restrict__ out)
{
    int row = blockIdx.x;
    int t = threadIdx.x;
    const float* xr = xin + (size_t)row * C_;
    float x0 = xr[t], x1 = xr[t + 256], x2 = xr[t + 512];
    float s1 = x0 + x1 + x2;
    float s2 = x0 * x0 + x1 * x1 + x2 * x2;
#pragma unroll
    for (int o = 32; o > 0; o >>= 1) {
        s1 += __shfl_xor(s1, o);
        s2 += __shfl_xor(s2, o);
    }
    __shared__ float red[8];
    if ((t & 63) == 0) { red[(t >> 6) * 2] = s1; red[(t >> 6) * 2 + 1] = s2; }
    __syncthreads();
    s1 = red[0] + red[2] + red[4] + red[6];
    s2 = red[1] + red[3] + red[5] + red[7];
    float m = s1 * (1.0f / 768.0f);
    float var = s2 * (1.0f / 768.0f) - m * m;
    float inv = rsqrtf(var + 1e-5f);
    ushort_t* orow = out + (size_t)row * C_;
    orow[t]       = f2b((x0 - m) * inv * g[t]       + bb[t]);
    orow[t + 256] = f2b((x1 - m) * inv * g[t + 256] + bb[t + 256]);
    orow[t + 512] = f2b((x2 - m) * inv * g[t + 512] + bb[t + 512]);
}

// ---------------- bf16 GEMM: 256x256 tile, 8 waves, ring-3, counted vmcnt -----
// A: [M,K] bf16 row-major, W: [Nf,K] bf16 row-major => out = A @ W^T + bias
// EPI 0: bf16 out = acc+bias ; EPI 1: bf16 out = gelu(acc+bias) ;
// EPI 2: fp32 out = acc+bias+resid(fp32)  (out may alias resid)
//
// m201 geometry on the verified ring pipeline: 512 threads / 8 waves, wave
// tile 128x64 (acc[8][4] = 128 VGPR), per K-step per wave: 12 ds_read_b128
// feeding 32 MFMA (reuse 2.67). LDS ring: 3 slots x (A 16KB + B 16KB) =
// 96KB -> 1 block/CU, 8 waves (2/SIMD, 256-VGPR budget, no launch_bounds cap).
// T2 swizzle (verified R4: conflicts -> 0): LDS slot s of row r holds global
// 16B segment s ^ ((r>>1)&3); staged via pre-swizzled GLOBAL source column
// c8s = ((lane&3)^((lane>>3)&3))*8 (LDS dst stays linear - gload_lds
// contract); reads use qswz = (quad*8) ^ (((row16>>1)&3)*8).
// Pipeline: stage(kt+2) into slot (kt-1)%3 (last read behind barrier kt-1);
// end of iter kt waits vmcnt(4) (confirm kt+1's 4 per-thread loads, FIFO);
// vmcnt never drains in steady state. setprio(1) around the MFMA cluster.
template <int EPI>
__global__ __launch_bounds__(512) void gemm_bt(
    const ushort_t* __restrict__ A, const ushort_t* __restrict__ W,
    const float* __restrict__ bias, const float* __restrict__ resid,
    void* __restrict__ outv, int M, int Nf, int K)
{
    __shared__ __align__(16) ushort_t ring[3][2][8192];  // 96 KB
    int t = threadIdx.x;
    int bm = blockIdx.x;   // M/256
    int bn = blockIdx.y;   // Nf/256
    int wave = t >> 6, lane = t & 63;
    int wm = (wave >> 2) * 128;          // wave row base: 0 or 128
    int wn = (wave & 3) * 64;            // wave col base: 0/64/128/192
    int row16 = lane & 15;
    int quad = lane >> 4;
    int qswz = (quad * 8) ^ (((row16 >> 1) & 3) * 8);  // read-side swizzle

    // staging: wave w stages rows [w*16,+16) and [(w+8)*16,+16) of both A,B.
    // lane i -> local row i/4, 16B-slot i%4; global source segment
    // pre-swizzled so LDS slot s holds segment s^((r>>1)&3).
    int rloc = lane >> 2;
    int c8s = ((lane & 3) ^ ((lane >> 3) & 3)) * 8;
    const ushort_t* Ag0 = A + (size_t)(bm * 256 + wave * 16 + rloc) * K + c8s;
    const ushort_t* Wg0 = W + (size_t)(bn * 256 + wave * 16 + rloc) * K + c8s;
    const size_t r128 = (size_t)128 * K;   // 128-row stride (elements)

    v4f acc[8][4];
#pragma unroll
    for (int i = 0; i < 8; i++)
#pragma unroll
        for (int j = 0; j < 4; j++) acc[i][j] = (v4f){0.f, 0.f, 0.f, 0.f};

    const int NT = K >> 5;   // K-tiles of 32 (24 or 96)

    auto STAGE = [&](int kt) {
        int s = kt % 3;
        ushort_t* a = &ring[s][0][0];
        ushort_t* b = &ring[s][1][0];
        size_t off = (size_t)kt * 32;
        GLOAD_LDS16(Ag0 + off,        a + wave * 512);
        GLOAD_LDS16(Ag0 + off + r128, a + (wave + 8) * 512);
        GLOAD_LDS16(Wg0 + off,        b + wave * 512);
        GLOAD_LDS16(Wg0 + off + r128, b + (wave + 8) * 512);
    };

    // prologue: 2 tiles in flight (8 per-thread loads), confirm tile 0
    STAGE(0);
    STAGE(1);
    asm volatile("s_waitcnt vmcnt(4)" ::: "memory");
    __builtin_amdgcn_s_barrier();

    for (int kt = 0; kt < NT; ++kt) {
        if (kt + 2 < NT) STAGE(kt + 2);          // into slot freed at kt-1

        const ushort_t* sA = &ring[kt % 3][0][0];
        const ushort_t* sB = &ring[kt % 3][1][0];
        v8bf af[8], bfr[4];
#pragma unroll
        for (int i = 0; i < 8; i++)
            af[i] = *(const v8bf*)(sA + (wm + i * 16 + row16) * 32 + qswz);
#pragma unroll
        for (int j = 0; j < 4; j++)
            bfr[j] = *(const v8bf*)(sB + (wn + j * 16 + row16) * 32 + qswz);
        __builtin_amdgcn_s_setprio(1);
#pragma unroll
        for (int i = 0; i < 8; i++)
#pragma unroll
            for (int j = 0; j < 4; j++)
                acc[i][j] = __builtin_amdgcn_mfma_f32_16x16x32_bf16(af[i], bfr[j], acc[i][j], 0, 0, 0);
        __builtin_amdgcn_s_setprio(0);

        if (kt + 1 < NT) {
            if (kt + 2 < NT)
                asm volatile("s_waitcnt vmcnt(4)" ::: "memory");  // confirm kt+1
            else
                asm volatile("s_waitcnt vmcnt(0)" ::: "memory");  // tail drain
            __builtin_amdgcn_s_barrier();
        }
    }

#pragma unroll
    for (int i = 0; i < 8; i++) {
#pragma unroll
        for (int j = 0; j < 4; j++) {
            int col = bn * 256 + wn + j * 16 + row16;
            float bv = bias[col];
#pragma unroll
            for (int r = 0; r < 4; r++) {
                int row = bm * 256 + wm + i * 16 + quad * 4 + r;
                float v = acc[i][j][r] + bv;
                if (EPI == 1) v = 0.5f * v * (1.0f + erff(v * 0.70710678118f));
                if (EPI == 2) {
                    v += resid[(size_t)row * Nf + col];
                    ((float*)outv)[(size_t)row * Nf + col] = v;
                } else {
                    ((ushort_t*)outv)[(size_t)row * Nf + col] = f2b(v);
                }
            }
        }
    }
}

// ---------------- channel attention: S = (q^T k)/32, P = softmax(S) ----------
__global__ __launch_bounds__(256) void chan_attn(
    const ushort_t* __restrict__ qkv, ushort_t* __restrict__ P)
{
    __shared__ __align__(16) char smem[96 * 97 * 4];
    ushort_t* sQ = (ushort_t*)smem;                 // [64][96] bf16
    ushort_t* sK = (ushort_t*)(smem + 64 * 96 * 2); // [64][96] bf16
    float* sS = (float*)smem;                       // [96][97] fp32 (after)
    int bg = blockIdx.x;
    int b = bg >> 3, g = bg & 7;
    int t = threadIdx.x;
    int tc = t >> 4, td = t & 15;   // 16x16 thread grid, 6x6 regs each
    float acc[6][6];
#pragma unroll
    for (int i = 0; i < 6; i++)
#pragma unroll
        for (int j = 0; j < 6; j++) acc[i][j] = 0.f;

    for (int n0 = 0; n0 < N_; n0 += 64) {
        __syncthreads();
#pragma unroll
        for (int i = 0; i < 3; i++) {
            int li = t + i * 256;           // 0..767, uint4 units (8 bf16)
            int r = li / 12, seg = li % 12;
            size_t qoff = ((size_t)(b * N_ + n0 + r) * 3 + 0) * C_ + g * HD_ + seg * 8;
            *(uint4*)(sQ + r * 96 + seg * 8) = *(const uint4*)(qkv + qoff);
            *(uint4*)(sK + r * 96 + seg * 8) = *(const uint4*)(qkv + qoff + C_);
        }
        __syncthreads();
#pragma unroll 4
        for (int n = 0; n < 64; n++) {
            float qv[6], kv[6];
#pragma unroll
            for (int i = 0; i < 6; i++) qv[i] = b2f(sQ[n * 96 + tc * 6 + i]);
#pragma unroll
            for (int j = 0; j < 6; j++) kv[j] = b2f(sK[n * 96 + td * 6 + j]);
#pragma unroll
            for (int i = 0; i < 6; i++)
#pragma unroll
                for (int j = 0; j < 6; j++) acc[i][j] += qv[i] * kv[j];
        }
    }
    __syncthreads();
#pragma unroll
    for (int i = 0; i < 6; i++)
#pragma unroll
        for (int j = 0; j < 6; j++)
            sS[(tc * 6 + i) * 97 + td * 6 + j] = acc[i][j] * 0.03125f;
    __syncthreads();
    if (t < 96) {
        float mx = -1e30f;
        for (int d = 0; d < 96; d++) mx = fmaxf(mx, sS[t * 97 + d]);
        float sum = 0.f;
        for (int d = 0; d < 96; d++) sum += __expf(sS[t * 97 + d] - mx);
        float rs = 1.0f / sum;
        ushort_t* prow = P + (size_t)bg * 9216 + t * 96;
        for (int d = 0; d < 96; d++) prow[d] = f2b(__expf(sS[t * 97 + d] - mx) * rs);
    }
}

// ---------------- attention apply: out[b,n,g,c] = sum_d P[c,d] * v[n,d] ------
__global__ __launch_bounds__(256) void attn_av(
    const ushort_t* __restrict__ qkv, const ushort_t* __restrict__ P,
    ushort_t* __restrict__ out)
{
    __shared__ __align__(16) ushort_t sP[96 * 96];  // 18KB bf16
    __shared__ __align__(16) ushort_t sV[64 * 96];  // 12KB bf16
    int blk = blockIdx.x;                 // b_local*128 + g*16 + nchunk
    int nch = blk & 15, g = (blk >> 4) & 7, b = blk >> 7;
    int t = threadIdx.x;
#pragma unroll
    for (int i = 0; i < 5; i++) {
        int li = t + i * 256;
        if (li < 1152)
            *(uint4*)(sP + li * 8) = *(const uint4*)(P + (size_t)(b * 8 + g) * 9216 + li * 8);
    }
    int n0 = nch * 64;
#pragma unroll
    for (int i = 0; i < 3; i++) {
        int li = t + i * 256;
        int r = li / 12, seg = li % 12;
        size_t voff = ((size_t)(b * N_ + n0 + r) * 3 + 2) * C_ + g * HD_ + seg * 8;
        *(uint4*)(sV + r * 96 + seg * 8) = *(const uint4*)(qkv + voff);
    }
    __syncthreads();
    int tn = t >> 4, tc = t & 15;   // 4 n's, 6 c's per thread
    float acc[4][6];
#pragma unroll
    for (int i = 0; i < 4; i++)
#pragma unroll
        for (int j = 0; j < 6; j++) acc[i][j] = 0.f;
#pragma unroll 4
    for (int d = 0; d < 96; d++) {
        float vv[4], pv[6];
#pragma unroll
        for (int i = 0; i < 4; i++) vv[i] = b2f(sV[(tn * 4 + i) * 96 + d]);
#pragma unroll
        for (int j = 0; j < 6; j++) pv[j] = b2f(sP[(tc * 6 + j) * 96 + d]);
#pragma unroll
        for (int i = 0; i < 4; i++)
#pragma unroll
            for (int j = 0; j < 6; j++) acc[i][j] += vv[i] * pv[j];
    }
#pragma unroll
    for (int i = 0; i < 4; i++) {
        int n = n0 + tn * 4 + i;
        size_t base = ((size_t)(b * N_ + n)) * C_ + g * HD_ + tc * 6;
#pragma unroll
        for (int j = 0; j < 6; j++) out[base + j] = f2b(acc[i][j]);
    }
}

// -----------------------------------------------------------------------------
// bf16-internal chunked pipeline. Residual chain (x1/x2/x3/out) fp32.
extern "C" void kernel_launch(void* const* d_in, const int* in_sizes, int n_in,
                              void* d_out, int out_size, void* d_ws, size_t ws_size,
                              hipStream_t stream)
{
    const float* x      = (const float*)d_in[0];
    const float* dw1_w  = (const float*)d_in[3];
    const float* dw1_b  = (const float*)d_in[4];
    const float* ln1_g  = (const float*)d_in[5];
    const float* ln1_b  = (const float*)d_in[6];
    const float* qkv_w  = (const float*)d_in[7];
    const float* qkv_b  = (const float*)d_in[8];
    const float* proj_w = (const float*)d_in[9];
    const float* proj_b = (const float*)d_in[10];
    const float* dw2_w  = (const float*)d_in[11];
    const float* dw2_b  = (const float*)d_in[12];
    const float* ln2_g  = (const float*)d_in[13];
    const float* ln2_b  = (const float*)d_in[14];
    const float* fc1_w  = (const float*)d_in[15];
    const float* fc1_b  = (const float*)d_in[16];
    const float* fc2_w  = (const float*)d_in[17];
    const float* fc2_b  = (const float*)d_in[18];
    float* outp = (float*)d_out;    // holds x1, then x3, then final out

    char* ws = (char*)d_ws;
    // bf16 weight arena
    ushort_t* qkvW = (ushort_t*)ws;                          // 2304*768
    ushort_t* projW = qkvW + 2304 * 768;                     // 768*768
    ushort_t* fc1W = projW + 768 * 768;                      // 3072*768
    ushort_t* fc2W = fc1W + 3072 * 768;                      // 768*3072
    const size_t WB = (size_t)(2304*768 + 768*768 + 3072*768 + 768*3072) * 2; // 14,155,776
    // transposed dwconv weights [9][768] fp32
    float* wt1 = (float*)(ws + WB);
    float* wt2 = wt1 + 9 * C_;
    const size_t WTB = 2 * 9 * C_ * sizeof(float);           // 55,296

    size_t CB = 32;
    while (CB > 1 && WB + WTB + CB * 12730368ull > ws_size) CB >>= 1;
    const size_t R = CB * 1024;
    char* act = ws + WB + WTB;
    ushort_t* L  = (ushort_t*)act;                           // [R,768] bf16
    ushort_t* Ab = (ushort_t*)(act + R * C_ * 2);            // [R,768] bf16
    float*    X2 = (float*)(act + 2 * R * C_ * 2);           // [R,768] fp32
    ushort_t* P  = (ushort_t*)(act + 2 * R * C_ * 2 + R * C_ * 4);
    ushort_t* D  = (ushort_t*)(act + 2 * R * C_ * 2 + R * C_ * 4 + CB * 147456);

    // 0. weight conversion fp32 -> bf16 ; dwconv weight transpose
    cvt_bf16<<<2304 * 768 / 1024, 256, 0, stream>>>(qkv_w, qkvW);
    cvt_bf16<<<768 * 768 / 1024, 256, 0, stream>>>(proj_w, projW);
    cvt_bf16<<<3072 * 768 / 1024, 256, 0, stream>>>(fc1_w, fc1W);
    cvt_bf16<<<768 * 3072 / 1024, 256, 0, stream>>>(fc2_w, fc2W);
    transpose_w<<<27, 256, 0, stream>>>(dw1_w, wt1);
    transpose_w<<<27, 256, 0, stream>>>(dw2_w, wt2);

    // 1. x1 = x + dwconv1(x) -> d_out  (full, fp32)
    dwconv_add<<<32 * 32 * 6, 256, 0, stream>>>(x, wt1, dw1_b, outp);

    const int nchunk = (int)(32 / CB);
    for (int c = 0; c < nchunk; c++) {
        float* xc = outp + (size_t)c * R * C_;   // x1 chunk, later x3 chunk
        // ln1 -> L (bf16)
        layernorm_bf<<<(int)R, 256, 0, stream>>>(xc, ln1_g, ln1_b, L);
        // qkv = L @ qkvW^T + b -> D (bf16)
        gemm_bt<0><<<dim3((int)R / 256, 2304 / 256), 512, 0, stream>>>(
            L, qkvW, qkv_b, nullptr, D, (int)R, 2304, C_);
        // P = softmax(q^T k / 32)
        chan_attn<<<(int)CB * 8, 256, 0, stream>>>(D, P);
        // A = P @ v (bf16)
        attn_av<<<(int)CB * 128, 256, 0, stream>>>(D, P, Ab);
        // x2 = x1 + A @ projW^T + b -> X2 (fp32)
        gemm_bt<2><<<dim3((int)R / 256, C_ / 256), 512, 0, stream>>>(
            Ab, projW, proj_b, xc, X2, (int)R, C_, C_);
        // x3 = x2 + dwconv2(x2) -> d_out chunk (fp32)
        dwconv_add<<<(int)(R / 1024) * 32 * 6, 256, 0, stream>>>(X2, wt2, dw2_b, xc);
        // ln2 -> L (bf16)
        layernorm_bf<<<(int)R, 256, 0, stream>>>(xc, ln2_g, ln2_b, L);
        // h = gelu(L @ fc1W^T + b) -> D (bf16)
        gemm_bt<1><<<dim3((int)R / 256, CH_ / 256), 512, 0, stream>>>(
            L, fc1W, fc1_b, nullptr, D, (int)R, CH_, C_);
        // out = x3 + h @ fc2W^T + b -> d_out chunk (fp32, alias-safe)
        gemm_bt<2><<<dim3((int)R / 256, C_ / 256), 512, 0, stream>>>(
            D, fc2W, fc2_b, xc, xc, (int)R, C_, CH_);
    }
}

// Round 6
// 1181.005 us; speedup vs baseline: 1.3286x; 1.3286x over previous
//
#include <hip/hip_runtime.h>

typedef unsigned short ushort_t;
typedef __bf16 v8bf __attribute__((ext_vector_type(8)));
typedef float v4f __attribute__((ext_vector_type(4)));

#define B_ 32
#define N_ 1024
#define C_ 768
#define G_ 8
#define HD_ 96
#define CH_ 3072
#define M_ 32768  // B*N

static __device__ __forceinline__ float b2f(ushort_t u) {
    union { float f; unsigned int i; } z; z.i = ((unsigned int)u) << 16; return z.f;
}
static __device__ __forceinline__ ushort_t f2b(float f) {
    unsigned int u = __float_as_uint(f);
    u += 0x7fff + ((u >> 16) & 1);   // RNE
    return (ushort_t)(u >> 16);
}
static __device__ __forceinline__ unsigned int pk2(float a, float b) {
    return (unsigned int)f2b(a) | ((unsigned int)f2b(b) << 16);
}

#define GLOAD_LDS16(g, l) __builtin_amdgcn_global_load_lds( \
    (const __attribute__((address_space(1))) unsigned int*)(g), \
    (__attribute__((address_space(3))) unsigned int*)(l), 16, 0, 0)

// ---------------- fp32 -> bf16 weight conversion (4 elems/thread) -------------
__global__ __launch_bounds__(256) void cvt_bf16(
    const float* __restrict__ in, ushort_t* __restrict__ out)
{
    int i = (blockIdx.x * 256 + threadIdx.x) * 4;
    float4 v = *(const float4*)(in + i);
    uint2 p; p.x = pk2(v.x, v.y); p.y = pk2(v.z, v.w);
    *(uint2*)(out + i) = p;
}

// ---------------- dwconv weight transpose: [C,3,3] -> [9][C] fp32 -------------
__global__ __launch_bounds__(256) void transpose_w(
    const float* __restrict__ w, float* __restrict__ wt)
{
    int i = blockIdx.x * 256 + threadIdx.x;   // exactly 6912 = 27*256
    int c = i / 9, k = i % 9;
    wt[k * C_ + c] = w[i];
}

// ---------------- depthwise 3x3 conv + residual (fp32): out = x + conv(x) ----
__global__ __launch_bounds__(256) void dwconv_add(
    const float* __restrict__ xin, const float* __restrict__ wt,
    const float* __restrict__ bias, float* __restrict__ out)
{
    int t = threadIdx.x;
    int bid = blockIdx.x;
    int cblk = bid % 6;                  // 6 = 768/128
    int bh = bid / 6;                    // b*32 + h
    int b = bh >> 5, h = bh & 31;
    int tw = t >> 5;                     // 0..7  -> 4-pixel group
    int c0 = cblk * 128 + (t & 31) * 4;  // channel base (float4)
    int w0 = tw * 4;

    float4 tap[3][6];
#pragma unroll
    for (int dh = 0; dh < 3; dh++) {
        int hh = h + dh - 1;
        bool hok = (hh >= 0) && (hh < 32);   // block-uniform branch
#pragma unroll
        for (int dw = 0; dw < 6; dw++) {
            int ww = w0 + dw - 1;
            bool ok = hok && (ww >= 0) && (ww < 32);
            if (ok)
                tap[dh][dw] = *(const float4*)(
                    xin + (size_t)((b << 10) | (hh << 5) | ww) * C_ + c0);
            else
                tap[dh][dw] = make_float4(0.f, 0.f, 0.f, 0.f);
        }
    }
    float4 wv[9];
#pragma unroll
    for (int k = 0; k < 9; k++)
        wv[k] = *(const float4*)(wt + k * C_ + c0);
    float4 bv = *(const float4*)(bias + c0);

#pragma unroll
    for (int i = 0; i < 4; i++) {
        float4 acc = bv;
#pragma unroll
        for (int dh = 0; dh < 3; dh++)
#pragma unroll
            for (int dw = 0; dw < 3; dw++) {
                float4 xv = tap[dh][i + dw];
                float4 wk = wv[dh * 3 + dw];
                acc.x += wk.x * xv.x; acc.y += wk.y * xv.y;
                acc.z += wk.z * xv.z; acc.w += wk.w * xv.w;
            }
        float4 xr = tap[1][i + 1];
        acc.x += xr.x; acc.y += xr.y; acc.z += xr.z; acc.w += xr.w;
        *(float4*)(out + (size_t)((b << 10) | (h << 5) | (w0 + i)) * C_ + c0) = acc;
    }
}

// ---------------- layernorm over C=768: fp32 in -> bf16 out -------------------
__global__ __launch_bounds__(256) void layernorm_bf(
    const float* __restrict__ xin, const float* __restrict__ g,
    const float* __restrict__ bb, ushort_t* __restrict__ out)
{
    int row = blockIdx.x;
    int t = threadIdx.x;
    const float* xr = xin + (size_t)row * C_;
    float x0 = xr[t], x1 = xr[t + 256], x2 = xr[t + 512];
    float s1 = x0 + x1 + x2;
    float s2 = x0 * x0 + x1 * x1 + x2 * x2;
#pragma unroll
    for (int o = 32; o > 0; o >>= 1) {
        s1 += __shfl_xor(s1, o);
        s2 += __shfl_xor(s2, o);
    }
    __shared__ float red[8];
    if ((t & 63) == 0) { red[(t >> 6) * 2] = s1; red[(t >> 6) * 2 + 1] = s2; }
    __syncthreads();
    s1 = red[0] + red[2] + red[4] + red[6];
    s2 = red[1] + red[3] + red[5] + red[7];
    float m = s1 * (1.0f / 768.0f);
    float var = s2 * (1.0f / 768.0f) - m * m;
    float inv = rsqrtf(var + 1e-5f);
    ushort_t* orow = out + (size_t)row * C_;
    orow[t]       = f2b((x0 - m) * inv * g[t]       + bb[t]);
    orow[t + 256] = f2b((x1 - m) * inv * g[t + 256] + bb[t + 256]);
    orow[t + 512] = f2b((x2 - m) * inv * g[t + 512] + bb[t + 512]);
}

// ---------------- bf16 GEMM: 128x128, ring-3, counted vmcnt, T2 swizzle -------
// (R4 known-good: fc2 146us, conflicts 0)
template <int EPI>
__global__ __launch_bounds__(256) void gemm_bt(
    const ushort_t* __restrict__ A, const ushort_t* __restrict__ W,
    const float* __restrict__ bias, const float* __restrict__ resid,
    void* __restrict__ outv, int M, int Nf, int K)
{
    __shared__ __align__(16) ushort_t ring[3][2][128 * 32];  // 48 KB
    int t = threadIdx.x;
    int bm = blockIdx.x;   // M/128
    int bn = blockIdx.y;   // Nf/128
    int wave = t >> 6, lane = t & 63;
    int wm = (wave >> 1) * 64;
    int wn = (wave & 1) * 64;
    int row16 = lane & 15;
    int quad = lane >> 4;
    int qswz = (quad * 8) ^ (((row16 >> 1) & 3) * 8);  // read-side swizzle

    int r0 = wave * 16 + (lane >> 2);
    int r1 = (wave + 4) * 16 + (lane >> 2);
    int c8s = ((lane & 3) ^ ((lane >> 3) & 3)) * 8;
    const ushort_t* Ag0 = A + (size_t)(bm * 128 + r0) * K + c8s;
    const ushort_t* Ag1 = A + (size_t)(bm * 128 + r1) * K + c8s;
    const ushort_t* Wg0 = W + (size_t)(bn * 128 + r0) * K + c8s;
    const ushort_t* Wg1 = W + (size_t)(bn * 128 + r1) * K + c8s;

    v4f acc[4][4];
#pragma unroll
    for (int i = 0; i < 4; i++)
#pragma unroll
        for (int j = 0; j < 4; j++) acc[i][j] = (v4f){0.f, 0.f, 0.f, 0.f};

    const int NT = K >> 5;   // K-tiles of 32

    auto STAGE = [&](int kt) {
        int s = kt % 3;
        ushort_t* a = &ring[s][0][0];
        ushort_t* b = &ring[s][1][0];
        int off = kt * 32;
        GLOAD_LDS16(Ag0 + off, a + wave * 512);
        GLOAD_LDS16(Ag1 + off, a + (wave + 4) * 512);
        GLOAD_LDS16(Wg0 + off, b + wave * 512);
        GLOAD_LDS16(Wg1 + off, b + (wave + 4) * 512);
    };

    STAGE(0);
    STAGE(1);
    asm volatile("s_waitcnt vmcnt(4)" ::: "memory");
    __builtin_amdgcn_s_barrier();

    for (int kt = 0; kt < NT; ++kt) {
        if (kt + 2 < NT) STAGE(kt + 2);          // into slot freed at kt-1

        const ushort_t* sA = &ring[kt % 3][0][0];
        const ushort_t* sB = &ring[kt % 3][1][0];
        v8bf af[4], bfr[4];
#pragma unroll
        for (int i = 0; i < 4; i++)
            af[i] = *(const v8bf*)(sA + (wm + i * 16 + row16) * 32 + qswz);
#pragma unroll
        for (int j = 0; j < 4; j++)
            bfr[j] = *(const v8bf*)(sB + (wn + j * 16 + row16) * 32 + qswz);
#pragma unroll
        for (int i = 0; i < 4; i++)
#pragma unroll
            for (int j = 0; j < 4; j++)
                acc[i][j] = __builtin_amdgcn_mfma_f32_16x16x32_bf16(af[i], bfr[j], acc[i][j], 0, 0, 0);

        if (kt + 1 < NT) {
            if (kt + 2 < NT)
                asm volatile("s_waitcnt vmcnt(4)" ::: "memory");  // confirm kt+1
            else
                asm volatile("s_waitcnt vmcnt(0)" ::: "memory");  // tail drain
            __builtin_amdgcn_s_barrier();
        }
    }

#pragma unroll
    for (int i = 0; i < 4; i++) {
#pragma unroll
        for (int j = 0; j < 4; j++) {
            int col = bn * 128 + wn + j * 16 + row16;
            float bv = bias[col];
#pragma unroll
            for (int r = 0; r < 4; r++) {
                int row = bm * 128 + wm + i * 16 + quad * 4 + r;
                float v = acc[i][j][r] + bv;
                if (EPI == 1) v = 0.5f * v * (1.0f + erff(v * 0.70710678118f));
                if (EPI == 2) {
                    v += resid[(size_t)row * Nf + col];
                    ((float*)outv)[(size_t)row * Nf + col] = v;
                } else {
                    ((ushort_t*)outv)[(size_t)row * Nf + col] = f2b(v);
                }
            }
        }
    }
}

// ---------------- channel attention (MFMA): S = (q^T k)/32, P = softmax(S) ---
// One block per (b_local, g). S[c,d] = sum_n q[n,c] k[n,d]: MFMA with
// A = Q^T [96c][n], B = K^T [96d][n], K-dim = n (1024, 16 chunks of 64).
// Q^T/K^T built during staging via scalar LDS transpose-writes into
// stride-72 rows (b128-aligned frag reads, 2-way banked; li=3t+i spreads
// n-rows across lanes so transpose-writes hit ~8 banks).
// MFMA: 4 waves = 2x2 of 48x48 (acc[3][3]).  Softmax phase as before.
__global__ __launch_bounds__(256) void chan_attn(
    const ushort_t* __restrict__ qkv, ushort_t* __restrict__ P)
{
    __shared__ __align__(16) char smem[96 * 97 * 4];   // 37,248 B
    ushort_t* sQt = (ushort_t*)smem;                   // [96][72] bf16
    ushort_t* sKt = (ushort_t*)(smem + 96 * 72 * 2);   // [96][72] bf16
    float* sS = (float*)smem;                          // [96][97] fp32 (after)
    int bg = blockIdx.x;
    int b = bg >> 3, g = bg & 7;
    int t = threadIdx.x;
    int wave = t >> 6, lane = t & 63;
    int wc = (wave >> 1) * 48, wd = (wave & 1) * 48;
    int row16 = lane & 15, quad = lane >> 4;

    v4f acc[3][3];
#pragma unroll
    for (int i = 0; i < 3; i++)
#pragma unroll
        for (int j = 0; j < 3; j++) acc[i][j] = (v4f){0.f, 0.f, 0.f, 0.f};

    for (int n0 = 0; n0 < N_; n0 += 64) {
        __syncthreads();                 // prev MFMA reads done
#pragma unroll
        for (int i = 0; i < 3; i++) {
            int li = t * 3 + i;          // 0..767: r spans 16 rows per wave
            int r = li / 12, sg = li % 12;
            size_t qoff = ((size_t)(b * N_ + n0 + r) * 3) * C_ + g * HD_ + sg * 8;
            union { uint4 v; ushort_t s[8]; } uq, uk;
            uq.v = *(const uint4*)(qkv + qoff);
            uk.v = *(const uint4*)(qkv + qoff + C_);
#pragma unroll
            for (int k = 0; k < 8; k++) {
                sQt[(sg * 8 + k) * 72 + r] = uq.s[k];
                sKt[(sg * 8 + k) * 72 + r] = uk.s[k];
            }
        }
        __syncthreads();                 // transpose visible
#pragma unroll
        for (int kk = 0; kk < 64; kk += 32) {
            v8bf af[3], bfr[3];
#pragma unroll
            for (int i = 0; i < 3; i++)
                af[i] = *(const v8bf*)(sQt + (wc + i * 16 + row16) * 72 + kk + quad * 8);
#pragma unroll
            for (int j = 0; j < 3; j++)
                bfr[j] = *(const v8bf*)(sKt + (wd + j * 16 + row16) * 72 + kk + quad * 8);
#pragma unroll
            for (int i = 0; i < 3; i++)
#pragma unroll
                for (int j = 0; j < 3; j++)
                    acc[i][j] = __builtin_amdgcn_mfma_f32_16x16x32_bf16(af[i], bfr[j], acc[i][j], 0, 0, 0);
        }
    }
    __syncthreads();                     // last MFMA reads done; reuse LDS as sS
#pragma unroll
    for (int i = 0; i < 3; i++)
#pragma unroll
        for (int j = 0; j < 3; j++)
#pragma unroll
            for (int r = 0; r < 4; r++) {
                int c = wc + i * 16 + quad * 4 + r;    // MFMA C: row = quad*4+reg
                int d = wd + j * 16 + row16;           // col = lane&15
                sS[c * 97 + d] = acc[i][j][r] * 0.03125f;
            }
    __syncthreads();
    if (t < 96) {
        float mx = -1e30f;
        for (int d = 0; d < 96; d++) mx = fmaxf(mx, sS[t * 97 + d]);
        float sum = 0.f;
        for (int d = 0; d < 96; d++) sum += __expf(sS[t * 97 + d] - mx);
        float rs = 1.0f / sum;
        ushort_t* prow = P + (size_t)bg * 9216 + t * 96;
        for (int d = 0; d < 96; d++) prow[d] = f2b(__expf(sS[t * 97 + d] - mx) * rs);
    }
}

// ---------------- attention apply (MFMA): out[n,c] = sum_d P[c,d] V[n,d] -----
// Per (b_local, g, nchunk of 256 rows): A = V[256n][96d], B = P[96c][96d],
// both K(d)-contiguous in memory -> straight GEMM. Rows padded to 104
// (2-way banked frag reads). 4 waves x 64 rows, acc[4][6], 3 K-steps.
__global__ __launch_bounds__(256) void attn_av(
    const ushort_t* __restrict__ qkv, const ushort_t* __restrict__ P,
    ushort_t* __restrict__ out)
{
    __shared__ __align__(16) ushort_t sV[256 * 104];  // 53,248 B
    __shared__ __align__(16) ushort_t sP[96 * 104];   // 19,968 B
    int blk = blockIdx.x;                 // b_local*32 + g*4 + nch
    int nch = blk & 3, g = (blk >> 2) & 7, b = blk >> 5;
    int t = threadIdx.x;
    int n0 = nch * 256;
#pragma unroll
    for (int i = 0; i < 12; i++) {
        int li = t + i * 256;             // 0..3071
        int r = li / 12, sg = li % 12;
        size_t voff = ((size_t)(b * N_ + n0 + r) * 3 + 2) * C_ + g * HD_ + sg * 8;
        *(uint4*)(sV + r * 104 + sg * 8) = *(const uint4*)(qkv + voff);
    }
#pragma unroll
    for (int i = 0; i < 5; i++) {
        int li = t + i * 256;
        if (li < 1152) {
            int r = li / 12, sg = li % 12;
            *(uint4*)(sP + r * 104 + sg * 8) =
                *(const uint4*)(P + (size_t)(b * 8 + g) * 9216 + li * 8);
        }
    }
    __syncthreads();
    int wave = t >> 6, lane = t & 63;
    int wm = wave * 64;
    int row16 = lane & 15, quad = lane >> 4;
    v4f acc[4][6];
#pragma unroll
    for (int i = 0; i < 4; i++)
#pragma unroll
        for (int j = 0; j < 6; j++) acc[i][j] = (v4f){0.f, 0.f, 0.f, 0.f};
#pragma unroll
    for (int kk = 0; kk < 96; kk += 32) {
        v8bf af[4], bfr[6];
#pragma unroll
        for (int i = 0; i < 4; i++)
            af[i] = *(const v8bf*)(sV + (wm + i * 16 + row16) * 104 + kk + quad * 8);
#pragma unroll
        for (int j = 0; j < 6; j++)
            bfr[j] = *(const v8bf*)(sP + (j * 16 + row16) * 104 + kk + quad * 8);
#pragma unroll
        for (int i = 0; i < 4; i++)
#pragma unroll
            for (int j = 0; j < 6; j++)
                acc[i][j] = __builtin_amdgcn_mfma_f32_16x16x32_bf16(af[i], bfr[j], acc[i][j], 0, 0, 0);
    }
#pragma unroll
    for (int i = 0; i < 4; i++)
#pragma unroll
        for (int j = 0; j < 6; j++)
#pragma unroll
            for (int r = 0; r < 4; r++) {
                int n = n0 + wm + i * 16 + quad * 4 + r;
                int c = j * 16 + row16;
                out[(size_t)(b * N_ + n) * C_ + g * HD_ + c] = f2b(acc[i][j][r]);
            }
}

// -----------------------------------------------------------------------------
// bf16-internal chunked pipeline. Residual chain (x1/x2/x3/out) fp32.
extern "C" void kernel_launch(void* const* d_in, const int* in_sizes, int n_in,
                              void* d_out, int out_size, void* d_ws, size_t ws_size,
                              hipStream_t stream)
{
    const float* x      = (const float*)d_in[0];
    const float* dw1_w  = (const float*)d_in[3];
    const float* dw1_b  = (const float*)d_in[4];
    const float* ln1_g  = (const float*)d_in[5];
    const float* ln1_b  = (const float*)d_in[6];
    const float* qkv_w  = (const float*)d_in[7];
    const float* qkv_b  = (const float*)d_in[8];
    const float* proj_w = (const float*)d_in[9];
    const float* proj_b = (const float*)d_in[10];
    const float* dw2_w  = (const float*)d_in[11];
    const float* dw2_b  = (const float*)d_in[12];
    const float* ln2_g  = (const float*)d_in[13];
    const float* ln2_b  = (const float*)d_in[14];
    const float* fc1_w  = (const float*)d_in[15];
    const float* fc1_b  = (const float*)d_in[16];
    const float* fc2_w  = (const float*)d_in[17];
    const float* fc2_b  = (const float*)d_in[18];
    float* outp = (float*)d_out;    // holds x1, then x3, then final out

    char* ws = (char*)d_ws;
    // bf16 weight arena
    ushort_t* qkvW = (ushort_t*)ws;                          // 2304*768
    ushort_t* projW = qkvW + 2304 * 768;                     // 768*768
    ushort_t* fc1W = projW + 768 * 768;                      // 3072*768
    ushort_t* fc2W = fc1W + 3072 * 768;                      // 768*3072
    const size_t WB = (size_t)(2304*768 + 768*768 + 3072*768 + 768*3072) * 2; // 14,155,776
    // transposed dwconv weights [9][768] fp32
    float* wt1 = (float*)(ws + WB);
    float* wt2 = wt1 + 9 * C_;
    const size_t WTB = 2 * 9 * C_ * sizeof(float);           // 55,296

    size_t CB = 32;
    while (CB > 1 && WB + WTB + CB * 12730368ull > ws_size) CB >>= 1;
    const size_t R = CB * 1024;
    char* act = ws + WB + WTB;
    ushort_t* L  = (ushort_t*)act;                           // [R,768] bf16
    ushort_t* Ab = (ushort_t*)(act + R * C_ * 2);            // [R,768] bf16
    float*    X2 = (float*)(act + 2 * R * C_ * 2);           // [R,768] fp32
    ushort_t* P  = (ushort_t*)(act + 2 * R * C_ * 2 + R * C_ * 4);
    ushort_t* D  = (ushort_t*)(act + 2 * R * C_ * 2 + R * C_ * 4 + CB * 147456);

    // 0. weight conversion fp32 -> bf16 ; dwconv weight transpose
    cvt_bf16<<<2304 * 768 / 1024, 256, 0, stream>>>(qkv_w, qkvW);
    cvt_bf16<<<768 * 768 / 1024, 256, 0, stream>>>(proj_w, projW);
    cvt_bf16<<<3072 * 768 / 1024, 256, 0, stream>>>(fc1_w, fc1W);
    cvt_bf16<<<768 * 3072 / 1024, 256, 0, stream>>>(fc2_w, fc2W);
    transpose_w<<<27, 256, 0, stream>>>(dw1_w, wt1);
    transpose_w<<<27, 256, 0, stream>>>(dw2_w, wt2);

    // 1. x1 = x + dwconv1(x) -> d_out  (full, fp32)
    dwconv_add<<<32 * 32 * 6, 256, 0, stream>>>(x, wt1, dw1_b, outp);

    const int nchunk = (int)(32 / CB);
    for (int c = 0; c < nchunk; c++) {
        float* xc = outp + (size_t)c * R * C_;   // x1 chunk, later x3 chunk
        // ln1 -> L (bf16)
        layernorm_bf<<<(int)R, 256, 0, stream>>>(xc, ln1_g, ln1_b, L);
        // qkv = L @ qkvW^T + b -> D (bf16)
        gemm_bt<0><<<dim3((int)R / 128, 2304 / 128), 256, 0, stream>>>(
            L, qkvW, qkv_b, nullptr, D, (int)R, 2304, C_);
        // P = softmax(q^T k / 32)  (MFMA)
        chan_attn<<<(int)CB * 8, 256, 0, stream>>>(D, P);
        // A = P @ v (MFMA)
        attn_av<<<(int)CB * 32, 256, 0, stream>>>(D, P, Ab);
        // x2 = x1 + A @ projW^T + b -> X2 (fp32)
        gemm_bt<2><<<dim3((int)R / 128, C_ / 128), 256, 0, stream>>>(
            Ab, projW, proj_b, xc, X2, (int)R, C_, C_);
        // x3 = x2 + dwconv2(x2) -> d_out chunk (fp32)
        dwconv_add<<<(int)(R / 1024) * 32 * 6, 256, 0, stream>>>(X2, wt2, dw2_b, xc);
        // ln2 -> L (bf16)
        layernorm_bf<<<(int)R, 256, 0, stream>>>(xc, ln2_g, ln2_b, L);
        // h = gelu(L @ fc1W^T + b) -> D (bf16)
        gemm_bt<1><<<dim3((int)R / 128, CH_ / 128), 256, 0, stream>>>(
            L, fc1W, fc1_b, nullptr, D, (int)R, CH_, C_);
        // out = x3 + h @ fc2W^T + b -> d_out chunk (fp32, alias-safe)
        gemm_bt<2><<<dim3((int)R / 128, C_ / 128), 256, 0, stream>>>(
            D, fc2W, fc2_b, xc, xc, (int)R, C_, CH_);
    }
}